// Round 7
// baseline (9278.650 us; speedup 1.0000x reference)
//
#include <hip/hip_runtime.h>
#include <stdint.h>

#define B_  16
#define T_  2048
#define D_  512

typedef short v8s __attribute__((ext_vector_type(8)));
typedef float v4f __attribute__((ext_vector_type(4)));
typedef unsigned u32x4 __attribute__((ext_vector_type(4)));

// ws layout (bytes)
#define WT_OFF    0u           // 8 MB bf16 weight fragments; REUSED as h rings after startup
#define H0_OFF    8388608u     // 32 MB linear h0 bf16 [t][d/8][b][8], sentinel-filled
#define H1_OFF    41943040u    // 32 MB linear h1
#define XB_OFF    75497472u    // 32 MB x packed bf16
#define SLACK_OFF 109051904u   // 4 KB tail (ws >= 109056000 verified by R0 run)

#define SENT 0xFFFFFFFFu       // two bf16 NaNs; |h|<=1.0 -> valid words never match

__device__ __forceinline__ short f2bf(float f) {
  unsigned u = __builtin_bit_cast(unsigned, f);
  u = (u + 0x7FFFu + ((u >> 16) & 1u)) >> 16;
  return (short)u;
}
__device__ __forceinline__ float sigmoid_fast(float z) { return 1.f / (1.f + __expf(-z)); }
__device__ __forceinline__ float tanh_fast(float z) {
  float e = __expf(2.f * z);
  return 1.f - 2.f / (e + 1.f);
}
__device__ __forceinline__ unsigned cohLoadU(const unsigned* p) {
  return __hip_atomic_load((unsigned*)p, __ATOMIC_RELAXED, __HIP_MEMORY_SCOPE_AGENT);
}
__device__ __forceinline__ unsigned long long cohLoadU2(const unsigned* p) {
  return __hip_atomic_load((unsigned long long*)p, __ATOMIC_RELAXED, __HIP_MEMORY_SCOPE_AGENT);
}
__device__ __forceinline__ void cohStoreU(unsigned* p, unsigned v) {
  __hip_atomic_store(p, v, __ATOMIC_RELAXED, __HIP_MEMORY_SCOPE_AGENT);
}
// L1-bypassing load: reads the XCD's L2 (same-XCD plain stores are visible there)
__device__ __forceinline__ unsigned sc0LoadU(const unsigned* p) {
  unsigned v;
  asm volatile("global_load_dword %0, %1, off sc0\n\ts_waitcnt vmcnt(0)"
               : "=v"(v) : "v"(p) : "memory");
  return v;
}

// Wx/Wh fp32 [L][512][2048] -> bf16 MFMA B-fragment order (validated R2-R6)
__global__ void prep_weights(const float* __restrict__ Wx, const float* __restrict__ Wh,
                             short* __restrict__ wT) {
  int tid = blockIdx.x * 256 + threadIdx.x;            // [0, 2^22)
  int l   = tid >> 21;
  int mat = (tid >> 20) & 1;
  int rem = tid & ((1 << 20) - 1);
  int k   = rem >> 11;
  int col = rem & 2047;
  const float* src = mat ? Wh : Wx;
  float v = src[(l << 20) + (k << 11) + col];
  int q = col >> 9, r9 = col & 511, g = r9 >> 3, jj = r9 & 7;
  int c = q * 8 + jj, ntile = c >> 4, n = c & 15;
  int kap = k >> 5, k5 = k & 31, quad = k5 >> 3, j = k5 & 7;
  int lane = quad * 16 + n;
  int dst = ((((l * 2 + mat) * 64 + g) * 2 + ntile) * 16 + kap) * 512 + lane * 8 + j;
  wT[dst] = f2bf(v);
}

// x pack + sentinel-fill linear h buffers + sentinel-fill the 4KB slack (handshake tables)
__global__ void prep_x(const float* __restrict__ x, short* __restrict__ xP,
                       unsigned* __restrict__ hwords, unsigned* __restrict__ slack) {
  int tid = blockIdx.x * 256 + threadIdx.x;            // [0, 2^24)
  hwords[tid] = SENT;
  if (tid < 1024) slack[tid] = SENT;
  int b = tid >> 20, r = tid & ((1 << 20) - 1), t = r >> 9, d = r & 511;
  xP[(size_t)t * 8192 + (d >> 3) * 128 + b * 8 + (d & 7)] = f2bf(x[tid]);
}

// 8 half-slice A-fragments via agent loads; running max (SENT detect)
__device__ __forceinline__ unsigned coh_load8(const short* p, v8s afr[8]) {
  unsigned mx = 0;
#pragma unroll
  for (int kk = 0; kk < 8; ++kk) {
    const unsigned* q = (const unsigned*)(p + kk * 512);
    unsigned long long w0 = cohLoadU2(q);
    unsigned long long w1 = cohLoadU2(q + 2);
    unsigned a = (unsigned)w0, b = (unsigned)(w0 >> 32);
    unsigned c = (unsigned)w1, d = (unsigned)(w1 >> 32);
    mx = a > mx ? a : mx;
    mx = b > mx ? b : mx;
    mx = c > mx ? c : mx;
    mx = d > mx ? d : mx;
    uint4 pk; pk.x = a; pk.y = b; pk.z = c; pk.w = d;
    afr[kk] = __builtin_bit_cast(v8s, pk);
  }
  return mx;
}

__device__ __forceinline__ void mfma32(const v8s afr[8], const v8s (&wfr)[4][8], v4f (&acc)[4]) {
#pragma unroll
  for (int kk = 0; kk < 8; ++kk) {
#pragma unroll
    for (int nt = 0; nt < 4; ++nt)
      acc[nt] = __builtin_amdgcn_mfma_f32_16x16x32_bf16(afr[kk], wfr[nt][kk], acc[nt], 0, 0, 0);
  }
}

// R4's proven agent-scope consume: speculative MFMA + one ballot + redo-on-fail
__device__ __forceinline__ void agent_consume(const short* hp, const v8s (&wfr)[4][8], v4f (&acc)[4]) {
  v8s a[8];
  unsigned mx = coh_load8(hp, a);
  mfma32(a, wfr, acc);
  if (__ballot(mx == SENT) != 0) {
    do {
      __builtin_amdgcn_s_sleep(1);
      mx = coh_load8(hp, a);
    } while (__ballot(mx == SENT) != 0);
#pragma unroll
    for (int nt = 0; nt < 4; ++nt) acc[nt] = (v4f){0.f, 0.f, 0.f, 0.f};
    mfma32(a, wfr, acc);
  }
}

__global__ __launch_bounds__(256, 1) void lstm_persist(
    const float* __restrict__ x, const short* __restrict__ xP,
    const short* wT, const float* __restrict__ bias,
    short* h0, short* h1, float* __restrict__ out, char* ws) {
  const int wg = blockIdx.x;
  if ((wg & 7) >= 2) return;      // 64 workers; idlers exit (grid 256 -> round-robin XCD pin)
  const int l = wg & 7;           // layer == preferred XCD id
  const int g = wg >> 3;          // 0..31 column group (16 h-cols)
  const int tid  = threadIdx.x;
  const int wave = tid >> 6;
  const int lane = tid & 63;
  const int m    = wave >> 1;     // 0 = input stream, 1 = own recurrence
  const int kh   = wave & 1;      // K-half
  const int n15  = lane & 15;
  const int quad = lane >> 4;

  __shared__ float LDSG[2][4][16][76];
  __shared__ int HS;

  short* hOwn = l ? h1 : h0;
  unsigned* hLinW = (unsigned*)hOwn;
  unsigned* ringOwn = (unsigned*)(ws + WT_OFF) + (size_t)l * (1u << 20);  // 256 slots x 4096 words
  unsigned* hsT = (unsigned*)(ws + SLACK_OFF);
  const int wid = l * 32 + g;

  // loop-invariant B fragments -> VGPRs (128 VGPR); MUST complete before ring writes
  v8s wfr[4][8];
#pragma unroll
  for (int nt = 0; nt < 4; ++nt) {
    const int gOld = 2 * g + (nt >> 1);
    const int nt2  = nt & 1;
    const short* wb = wT + (size_t)((((l * 2 + m) * 64 + gOld) * 2 + nt2) * 16 + kh * 8) * 512 + lane * 8;
#pragma unroll
    for (int kk = 0; kk < 8; ++kk) wfr[nt][kk] = *(const v8s*)(wb + kk * 512);
  }
  // epilogue state (waves 0,1)
  const int eIdx = wave * 64 + lane;
  const int bb = eIdx >> 3, jp = eIdx & 7;
  const int hi = jp >> 2;
  const int jj = 2 * (jp & 3);
  float bq[4][2];
#pragma unroll
  for (int q = 0; q < 4; ++q) {
    bq[q][0] = bias[l * 2048 + q * 512 + g * 16 + 2 * jp];
    bq[q][1] = bias[l * 2048 + q * 512 + g * 16 + 2 * jp + 1];
  }
  asm volatile("s_waitcnt vmcnt(0)" ::: "memory");   // weights + bias resident

  // ---- placement handshake: is my whole layer on my XCD, L2-rendezvous-visible? ----
  if (wave == 0) {
    unsigned myxcc;
    asm volatile("s_getreg_b32 %0, hwreg(20, 0, 32)" : "=s"(myxcc));  // HW_REG_XCC_ID (gfx940+)
    myxcc &= 0xFFu;
    if (lane == 0) {
#pragma unroll
      for (int r = 0; r < 4; ++r) hsT[r * 64 + wid] = 0xA5A50000u + r;  // plain -> own L2
      cohStoreU(&hsT[256 + wid], 0xB0000000u | myxcc);                  // agent (reliable)
    }
    bool mine = true;
    if (lane < 32) {
      const int p = l * 32 + lane;
      unsigned long long dl = __builtin_amdgcn_s_memrealtime() + 400000ull;
      for (;;) {
        bool ok = true;
#pragma unroll
        for (int r = 0; r < 4; ++r) ok = ok && (sc0LoadU(&hsT[r * 64 + p]) == 0xA5A50000u + r);
        ok = ok && (cohLoadU(&hsT[256 + p]) == (0xB0000000u | myxcc));
        if (ok) break;
        if (__builtin_amdgcn_s_memrealtime() > dl) { mine = false; break; }
        __builtin_amdgcn_s_sleep(2);
      }
    }
    const bool myBit = (__ballot(mine ? 1 : 0) == ~0ull);
    if (lane == 0) cohStoreU(&hsT[320 + wid], 0xC0000000u | (myBit ? 1u : 0u));
    // agreement round (no timeout; bit-store above is unconditional -> terminates):
    // all layer-mates converge on the identical fast/slow decision, which also
    // sequences everyone's ring writes after everyone's weight loads.
    bool agree = true;
    if (lane < 32) {
      const int p = l * 32 + lane;
      unsigned v;
      do { v = cohLoadU(&hsT[320 + p]); if (v == SENT) __builtin_amdgcn_s_sleep(2); } while (v == SENT);
      agree = (v & 1u) != 0u;
    }
    const bool fastLayer = (__ballot(agree ? 1 : 0) == ~0ull);
    if (lane == 0) HS = fastLayer ? 1 : 0;
  }
  __syncthreads();
  const bool fastL = (HS != 0);

  float c0 = 0.f, c1 = 0.f;
  const int aOff  = kh * 4096 + quad * 128 + n15 * 8;  // short offset in a t-slice
  const int wOffA = kh * 2048 + quad * 64 + n15 * 4;   // u32 word offset
  bool useFast = fastL;
  int fails = 0;
  u32x4 pf[8];                                          // cross-stream prefetch regs (l1, m0)

  for (int t = 0; t < T_; ++t) {
    const int buf = t & 1;

    float2 xv;
    size_t xi = 0;
    if (l == 1 && wave < 2) {
      xi = (size_t)bb * (T_ * D_) + (size_t)t * D_ + g * 16 + 2 * jp;
      xv = *(const float2*)(x + xi);
    }

    v4f acc[4];
#pragma unroll
    for (int nt = 0; nt < 4; ++nt) acc[nt] = (v4f){0.f, 0.f, 0.f, 0.f};

    if (m == 0) {
      if (l == 0) {
        const short* p = xP + (size_t)t * 8192 + aOff;   // static input, plain loads
        v8s afr[8];
#pragma unroll
        for (int kk = 0; kk < 8; ++kk) afr[kk] = *(const v8s*)(p + kk * 512);
        mfma32(afr, wfr, acc);
      } else {
        // cross stream h0(t): prefetched last step (agent, sentinel-safe linear buffer)
        bool ok = false;
        if (t > 0) {
          unsigned mx = 0;
#pragma unroll
          for (int kk = 0; kk < 8; ++kk) {
            unsigned a_ = pf[kk].x > pf[kk].y ? pf[kk].x : pf[kk].y;
            unsigned b_ = pf[kk].z > pf[kk].w ? pf[kk].z : pf[kk].w;
            unsigned m_ = a_ > b_ ? a_ : b_;
            mx = m_ > mx ? m_ : mx;
          }
          if (__ballot(mx == SENT) == 0ull) {
            v8s a[8];
#pragma unroll
            for (int kk = 0; kk < 8; ++kk) a[kk] = __builtin_bit_cast(v8s, pf[kk]);
            mfma32(a, wfr, acc);
            ok = true;
          }
        }
        if (!ok) agent_consume(h0 + (size_t)t * 8192 + aOff, wfr, acc);
        if (t + 1 < T_) {                                // issue prefetch for t+1
          const unsigned* q = (const unsigned*)(h0 + (size_t)(t + 1) * 8192 + aOff);
#pragma unroll
          for (int kk = 0; kk < 8; ++kk) {
            unsigned long long w0 = cohLoadU2(q + kk * 256);
            unsigned long long w1 = cohLoadU2(q + kk * 256 + 2);
            u32x4 v; v.x = (unsigned)w0; v.y = (unsigned)(w0 >> 32);
            v.z = (unsigned)w1; v.w = (unsigned)(w1 >> 32);
            pf[kk] = v;
          }
        }
      }
    } else if (t > 0) {
      // own recurrence h(t-1)
      bool got = false;
      if (useFast && t >= 129) {
        const unsigned* rp = ringOwn + (unsigned)((t - 1) & 255) * 4096 + wOffA;
        for (int pass = 0; pass < 64; ++pass) {
          u32x4 u[8];
#pragma unroll
          for (int kk = 0; kk < 8; ++kk) {
            const unsigned* p = rp + kk * 256;
            asm volatile("global_load_dwordx4 %0, %1, off sc0" : "=v"(u[kk]) : "v"(p) : "memory");
          }
          asm volatile("s_waitcnt vmcnt(0)" ::: "memory");
          __builtin_amdgcn_sched_barrier(0);             // rule #18: pin MFMA after the wait
          unsigned mx = 0;
#pragma unroll
          for (int kk = 0; kk < 8; ++kk) {
            unsigned a_ = u[kk].x > u[kk].y ? u[kk].x : u[kk].y;
            unsigned b_ = u[kk].z > u[kk].w ? u[kk].z : u[kk].w;
            unsigned m_ = a_ > b_ ? a_ : b_;
            mx = m_ > mx ? m_ : mx;
          }
          if (__ballot(mx == SENT) == 0ull) {
#pragma unroll
            for (int kk = 0; kk < 8; ++kk) {
              v8s a_ = __builtin_bit_cast(v8s, u[kk]);
#pragma unroll
              for (int nt = 0; nt < 4; ++nt)
                acc[nt] = __builtin_amdgcn_mfma_f32_16x16x32_bf16(a_, wfr[nt][kk], acc[nt], 0, 0, 0);
            }
            got = true;
            break;
          }
        }
        if (!got) { if (++fails > 16) useFast = false; }
      }
      if (!got) agent_consume(hOwn + (size_t)(t - 1) * 8192 + aOff, wfr, acc);
    }

#pragma unroll
    for (int nt = 0; nt < 4; ++nt) {
      const int rb = quad * 4;
#pragma unroll
      for (int r = 0; r < 4; ++r)
        LDSG[buf][wave][rb + r][nt * 16 + n15] = acc[nt][r];
    }
    __syncthreads();

    // ---------- epilogue on waves 0+1 ----------
    if (wave < 2) {
      float2 s[4];
#pragma unroll
      for (int q = 0; q < 4; ++q) {
        const int coff = (hi * 2 + (q >> 1)) * 16 + (q & 1) * 8 + jj;
        float2 a0 = *(const float2*)&LDSG[buf][0][bb][coff];
        float2 a1 = *(const float2*)&LDSG[buf][1][bb][coff];
        float2 a2 = *(const float2*)&LDSG[buf][2][bb][coff];
        float2 a3 = *(const float2*)&LDSG[buf][3][bb][coff];
        s[q].x = a0.x + a1.x + a2.x + a3.x + bq[q][0];
        s[q].y = a0.y + a1.y + a2.y + a3.y + bq[q][1];
      }
      float i0 = sigmoid_fast(s[0].x), i1 = sigmoid_fast(s[0].y);
      float f0 = sigmoid_fast(s[1].x), f1 = sigmoid_fast(s[1].y);
      float g0 = tanh_fast(s[2].x),    g1 = tanh_fast(s[2].y);
      float o0 = sigmoid_fast(s[3].x), o1 = sigmoid_fast(s[3].y);
      c0 = f0 * c0 + i0 * g0;
      c1 = f1 * c1 + i1 * g1;
      float h0v = o0 * tanh_fast(c0);
      float h1v = o1 * tanh_fast(c1);
      unsigned pack = (unsigned)(unsigned short)f2bf(h0v) |
                      ((unsigned)(unsigned short)f2bf(h1v) << 16);
      const unsigned woff = (2u * g + hi) * 64 + bb * 4 + (jp & 3);
      cohStoreU(hLinW + (size_t)t * 4096 + woff, pack);          // agent (always; fallback+cross)
      if (fastL && t >= 8) {
        ringOwn[(unsigned)(t & 255) * 4096 + woff] = pack;        // plain -> own-XCD L2
        ringOwn[(unsigned)((t + 120) & 255) * 4096 + woff] = SENT; // re-poison 120 steps ahead
      }
      if (l == 1) {
        float2 ov; ov.x = h0v + xv.x; ov.y = h1v + xv.y;
        *(float2*)(out + xi) = ov;
      }
    }
  }
}

extern "C" void kernel_launch(void* const* d_in, const int* in_sizes, int n_in,
                              void* d_out, int out_size, void* d_ws, size_t ws_size,
                              hipStream_t stream) {
  const float* x    = (const float*)d_in[0];
  const float* Wx   = (const float*)d_in[1];
  const float* Wh   = (const float*)d_in[2];
  const float* bias = (const float*)d_in[3];
  float* out = (float*)d_out;

  char* ws   = (char*)d_ws;
  short* wT  = (short*)(ws + WT_OFF);
  short* h0  = (short*)(ws + H0_OFF);
  short* h1  = (short*)(ws + H1_OFF);
  short* xP  = (short*)(ws + XB_OFF);
  unsigned* hwords = (unsigned*)(ws + H0_OFF);
  unsigned* slack  = (unsigned*)(ws + SLACK_OFF);

  hipLaunchKernelGGL(prep_weights, dim3(16384), dim3(256), 0, stream, Wx, Wh, wT);
  hipLaunchKernelGGL(prep_x, dim3(65536), dim3(256), 0, stream, x, xP, hwords, slack);
  hipLaunchKernelGGL(lstm_persist, dim3(256), dim3(256), 0, stream,
                     x, xP, wT, bias, h0, h1, out, ws);
}